// Round 3
// baseline (188.842 us; speedup 1.0000x reference)
//
#include <hip/hip_runtime.h>
#include <hip/hip_cooperative_groups.h>

namespace cg = cooperative_groups;

#define DDIM  256
#define NSLOT 64   // atomic accumulator slots: 64*256 floats = 64 KB

// g = (X W)(X^T (X b)) computed as u=Xb, v=X^T u, w2=W v, g=X w2.
// One cooperative launch, 512 blocks x 256 threads (2 blocks/CU, co-resident).
// Phase1+3 assign each block the SAME 32 rows of X -> second pass hits L2.
__global__ __launch_bounds__(256) void fused_g(const float* __restrict__ X,
                                               const float* __restrict__ W,
                                               const float* __restrict__ b,
                                               float* __restrict__ g,
                                               float* __restrict__ vslots,
                                               float* __restrict__ w2) {
    cg::grid_group grid = cg::this_grid();
    const int tid  = threadIdx.x;
    const int lane = tid & 63;
    const int wave = tid >> 6;
    const int bid  = blockIdx.x;
    const float4* X4 = (const float4*)X;

    // ---- phase 1: per-row t = x.b (butterfly), vacc += t*x; 8 rows/wave ----
    {
        const float4 bf = ((const float4*)b)[lane];
        float4 vacc = make_float4(0.f, 0.f, 0.f, 0.f);
        const int row0 = bid * 32 + wave * 8;
        #pragma unroll
        for (int i = 0; i < 8; ++i) {
            const float4 x = X4[(row0 + i) * 64 + lane];
            float t = x.x * bf.x + x.y * bf.y + x.z * bf.z + x.w * bf.w;
            #pragma unroll
            for (int off = 32; off; off >>= 1) t += __shfl_xor(t, off, 64);
            vacc.x += t * x.x; vacc.y += t * x.y;
            vacc.z += t * x.z; vacc.w += t * x.w;
        }
        __shared__ float sp[4][DDIM];
        ((float4*)sp[wave])[lane] = vacc;
        __syncthreads();
        const float s = sp[0][tid] + sp[1][tid] + sp[2][tid] + sp[3][tid];
        // 512 blocks over 64 slots: only 8 atomic adds per address — no hotspot
        atomicAdd(&vslots[(bid & (NSLOT - 1)) * DDIM + tid], s);
    }
    __threadfence();
    grid.sync();

    // ---- phase 2 (blocks 0..63): v = sum(slots); w2 = W v, wave-per-row ----
    if (bid < NSLOT) {
        float s = 0.f;
        #pragma unroll 8
        for (int j = 0; j < NSLOT; ++j) s += vslots[j * DDIM + tid];  // coalesced
        __shared__ __align__(16) float sv[DDIM];
        sv[tid] = s;
        __syncthreads();
        const float4 vf = ((const float4*)sv)[lane];
        const int row = bid * 4 + wave;
        const float4 w = ((const float4*)W)[row * 64 + lane];
        float t = w.x * vf.x + w.y * vf.y + w.z * vf.z + w.w * vf.w;
        #pragma unroll
        for (int off = 32; off; off >>= 1) t += __shfl_xor(t, off, 64);
        if (lane == 0) w2[row] = t;
        __threadfence();
    }
    grid.sync();

    // ---- phase 3: g = X w2 over the same rows (X warm in this XCD's L2) ----
    {
        const float4 wf = ((const float4*)w2)[lane];
        const int row0 = bid * 32 + wave * 8;
        #pragma unroll
        for (int i = 0; i < 8; ++i) {
            const float4 x = X4[(row0 + i) * 64 + lane];
            float t = x.x * wf.x + x.y * wf.y + x.z * wf.z + x.w * wf.w;
            #pragma unroll
            for (int off = 32; off; off >>= 1) t += __shfl_xor(t, off, 64);
            if (lane == 0) g[row0 + i] = t;
        }
    }
}

extern "C" void kernel_launch(void* const* d_in, const int* in_sizes, int n_in,
                              void* d_out, int out_size, void* d_ws, size_t ws_size,
                              hipStream_t stream) {
    const float* X = (const float*)d_in[0];   // (16384, 256)
    const float* W = (const float*)d_in[1];   // (256, 256)
    const float* b = (const float*)d_in[2];   // (256,)
    float* out = (float*)d_out;               // (16384,)

    float* vslots = (float*)d_ws;             // 64 * 256 floats
    float* w2     = vslots + NSLOT * DDIM;    // 256 floats

    hipMemsetAsync(vslots, 0, NSLOT * DDIM * sizeof(float), stream);

    void* args[] = { (void*)&X, (void*)&W, (void*)&b,
                     (void*)&out, (void*)&vslots, (void*)&w2 };
    hipLaunchCooperativeKernel(reinterpret_cast<void*>(fused_g),
                               dim3(512), dim3(256), args, 0, stream);
}

// Round 5
// 77.555 us; speedup vs baseline: 2.4349x; 2.4349x over previous
//
#include <hip/hip_runtime.h>

#define NROWS 16384
#define DDIM  256
#define K1BLK 512   // k1 grid: 2 blocks/CU, 8 rows/wave

// g = (X W)(X^T (X b)) via u = Xb, v = X^T u, w2 = W v, g = X w2.
// 3 plain kernels, no atomics, no memset — fully deterministic.

// ---------------------------------------------------------------------------
// k1: partial v per block. Wave-per-row (lane l holds cols 4l..4l+3):
//   t = x.b (6-step butterfly) ; vacc += t * x ; 8 rows/wave x 4 waves = 32 rows.
// Block combines wave partials in LDS, writes partials[bid][0..255] coalesced.
// ---------------------------------------------------------------------------
__global__ __launch_bounds__(256) void k1_partial_v(const float* __restrict__ X,
                                                    const float* __restrict__ b,
                                                    float* __restrict__ partials) {
    const int tid  = threadIdx.x;
    const int lane = tid & 63;
    const int wave = tid >> 6;
    const int bid  = blockIdx.x;

    const float4* X4 = (const float4*)X;
    const float4  bf = ((const float4*)b)[lane];

    float4 vacc = make_float4(0.f, 0.f, 0.f, 0.f);
    const int row0 = bid * 32 + wave * 8;
    #pragma unroll
    for (int i = 0; i < 8; ++i) {
        const float4 x = X4[(row0 + i) * 64 + lane];
        float t = x.x * bf.x + x.y * bf.y + x.z * bf.z + x.w * bf.w;
        #pragma unroll
        for (int off = 32; off; off >>= 1) t += __shfl_xor(t, off, 64);
        vacc.x += t * x.x; vacc.y += t * x.y;
        vacc.z += t * x.z; vacc.w += t * x.w;
    }

    __shared__ float sp[4][DDIM];
    ((float4*)sp[wave])[lane] = vacc;
    __syncthreads();
    // every column tid: all 4 wave partials were written for all 256 cols
    partials[bid * DDIM + tid] = sp[0][tid] + sp[1][tid] + sp[2][tid] + sp[3][tid];
}

// ---------------------------------------------------------------------------
// k2: 64 blocks. Correct 2D reduce of partials[512][256]:
//   thread t owns float4 col-group c4 = lane (cols 4*lane..4*lane+3) and
//   row segment seg = wave (rows seg*128..seg*128+127). Vectorized coalesced
//   16B loads. sp4[seg][c4] -> every cell written. Then per-column combine
//   of the 4 segments, then wave-per-row w2 = W v (4 rows/block).
// ---------------------------------------------------------------------------
__global__ __launch_bounds__(256) void k2_w2(const float* __restrict__ partials,
                                             const float* __restrict__ W,
                                             float* __restrict__ w2) {
    const int tid  = threadIdx.x;
    const int lane = tid & 63;   // float4 column group
    const int wave = tid >> 6;   // row segment

    const float4* P4 = (const float4*)partials;
    float4 acc = make_float4(0.f, 0.f, 0.f, 0.f);
    const int r0 = wave * (K1BLK / 4);
    #pragma unroll 8
    for (int j = 0; j < K1BLK / 4; ++j) {
        const float4 p = P4[(r0 + j) * 64 + lane];
        acc.x += p.x; acc.y += p.y; acc.z += p.z; acc.w += p.w;
    }

    __shared__ float4 sp4[4][64];
    sp4[wave][lane] = acc;
    __syncthreads();

    // flat view: spf[seg*256 + col], col 0..255 (float4 c4 holds cols 4c4..4c4+3)
    const float* spf = (const float*)sp4;
    __shared__ __align__(16) float sv[DDIM];
    sv[tid] = spf[tid] + spf[256 + tid] + spf[512 + tid] + spf[768 + tid];
    __syncthreads();

    const float4 vf = ((const float4*)sv)[lane];
    const int row = blockIdx.x * 4 + wave;
    const float4 w = ((const float4*)W)[row * 64 + lane];
    float t = w.x * vf.x + w.y * vf.y + w.z * vf.z + w.w * vf.w;
    #pragma unroll
    for (int off = 32; off; off >>= 1) t += __shfl_xor(t, off, 64);
    if (lane == 0) w2[row] = t;
}

// ---------------------------------------------------------------------------
// k3: g = X w2. 1024 blocks (4/CU), 4 rows/wave, wave-per-row butterfly dot.
// ---------------------------------------------------------------------------
__global__ __launch_bounds__(256) void k3_g(const float* __restrict__ X,
                                            const float* __restrict__ w2,
                                            float* __restrict__ g) {
    const int tid  = threadIdx.x;
    const int lane = tid & 63;
    const int wave = tid >> 6;

    const float4* X4 = (const float4*)X;
    const float4  wf = ((const float4*)w2)[lane];

    const int row0 = blockIdx.x * 16 + wave * 4;
    #pragma unroll
    for (int i = 0; i < 4; ++i) {
        const float4 x = X4[(row0 + i) * 64 + lane];
        float t = x.x * wf.x + x.y * wf.y + x.z * wf.z + x.w * wf.w;
        #pragma unroll
        for (int off = 32; off; off >>= 1) t += __shfl_xor(t, off, 64);
        if (lane == 0) g[row0 + i] = t;
    }
}

extern "C" void kernel_launch(void* const* d_in, const int* in_sizes, int n_in,
                              void* d_out, int out_size, void* d_ws, size_t ws_size,
                              hipStream_t stream) {
    const float* X = (const float*)d_in[0];   // (16384, 256)
    const float* W = (const float*)d_in[1];   // (256, 256)
    const float* b = (const float*)d_in[2];   // (256,)
    float* out = (float*)d_out;               // (16384,)

    float* partials = (float*)d_ws;              // 512 * 256 floats = 512 KB
    float* w2       = partials + K1BLK * DDIM;   // 256 floats

    k1_partial_v<<<K1BLK, 256, 0, stream>>>(X, b, partials);
    k2_w2<<<64, 256, 0, stream>>>(partials, W, w2);
    k3_g<<<1024, 256, 0, stream>>>(X, w2, out);
}

// Round 6
// 73.409 us; speedup vs baseline: 2.5725x; 1.0565x over previous
//
#include <hip/hip_runtime.h>

#define NROWS 16384
#define DDIM  256
#define K1BLK 1024  // 4 blocks/CU -> 16 waves/CU for latency hiding
#define NSLOT 64    // atomic accumulator slots: 64*256 floats = 64 KB

// g = (X W)(X^T (X b)) via u = Xb, v = X^T u, w2 = W v, g = X w2.

// ---------------------------------------------------------------------------
// k1: per-row t = x.b (6-step butterfly), vacc += t*x; 4 rows/wave x 4 waves.
// Block combines wave partials in LDS, then 256 coalesced atomicAdds into
// slot (bid & 63): 1024 blocks / 64 slots = 16 adds per address — no hotspot.
// ---------------------------------------------------------------------------
__global__ __launch_bounds__(256) void k1_v(const float* __restrict__ X,
                                            const float* __restrict__ b,
                                            float* __restrict__ slots) {
    const int tid  = threadIdx.x;
    const int lane = tid & 63;
    const int wave = tid >> 6;
    const int bid  = blockIdx.x;

    const float4* X4 = (const float4*)X;
    const float4  bf = ((const float4*)b)[lane];

    float4 vacc = make_float4(0.f, 0.f, 0.f, 0.f);
    const int row0 = bid * 16 + wave * 4;
    #pragma unroll
    for (int i = 0; i < 4; ++i) {
        const float4 x = X4[(row0 + i) * 64 + lane];
        float t = x.x * bf.x + x.y * bf.y + x.z * bf.z + x.w * bf.w;
        #pragma unroll
        for (int off = 32; off; off >>= 1) t += __shfl_xor(t, off, 64);
        vacc.x += t * x.x; vacc.y += t * x.y;
        vacc.z += t * x.z; vacc.w += t * x.w;
    }

    __shared__ float sp[4][DDIM];
    ((float4*)sp[wave])[lane] = vacc;
    __syncthreads();
    const float s = sp[0][tid] + sp[1][tid] + sp[2][tid] + sp[3][tid];
    atomicAdd(&slots[(bid & (NSLOT - 1)) * DDIM + tid], s);  // coalesced per wave
}

// ---------------------------------------------------------------------------
// k2: 64 blocks. Reduce slots[64][256] (64 KB, L2-resident): thread
// (wave,lane) sums 16 slot-rows of float4 col-group lane -> sp4[4][64] (every
// cell written), per-column combine -> v in LDS, then wave-per-row w2 = W v
// (rows bid*4+wave; each block reads only its 4 KB of W).
// ---------------------------------------------------------------------------
__global__ __launch_bounds__(256) void k2_w2(const float* __restrict__ slots,
                                             const float* __restrict__ W,
                                             float* __restrict__ w2) {
    const int tid  = threadIdx.x;
    const int lane = tid & 63;   // float4 column group
    const int wave = tid >> 6;   // slot-row segment

    const float4* S4 = (const float4*)slots;
    float4 acc = make_float4(0.f, 0.f, 0.f, 0.f);
    const int r0 = wave * (NSLOT / 4);
    #pragma unroll
    for (int j = 0; j < NSLOT / 4; ++j) {
        const float4 p = S4[(r0 + j) * 64 + lane];
        acc.x += p.x; acc.y += p.y; acc.z += p.z; acc.w += p.w;
    }

    __shared__ float4 sp4[4][64];
    sp4[wave][lane] = acc;
    __syncthreads();

    const float* spf = (const float*)sp4;  // spf[seg*256 + col]
    __shared__ __align__(16) float sv[DDIM];
    sv[tid] = spf[tid] + spf[256 + tid] + spf[512 + tid] + spf[768 + tid];
    __syncthreads();

    const float4 vf = ((const float4*)sv)[lane];
    const int row = blockIdx.x * 4 + wave;
    const float4 w = ((const float4*)W)[row * 64 + lane];
    float t = w.x * vf.x + w.y * vf.y + w.z * vf.z + w.w * vf.w;
    #pragma unroll
    for (int off = 32; off; off >>= 1) t += __shfl_xor(t, off, 64);
    if (lane == 0) w2[row] = t;
}

// ---------------------------------------------------------------------------
// k3: g = X w2. 1024 blocks (4/CU), 4 rows/wave, wave-per-row butterfly dot.
// ---------------------------------------------------------------------------
__global__ __launch_bounds__(256) void k3_g(const float* __restrict__ X,
                                            const float* __restrict__ w2,
                                            float* __restrict__ g) {
    const int tid  = threadIdx.x;
    const int lane = tid & 63;
    const int wave = tid >> 6;

    const float4* X4 = (const float4*)X;
    const float4  wf = ((const float4*)w2)[lane];

    const int row0 = blockIdx.x * 16 + wave * 4;
    #pragma unroll
    for (int i = 0; i < 4; ++i) {
        const float4 x = X4[(row0 + i) * 64 + lane];
        float t = x.x * wf.x + x.y * wf.y + x.z * wf.z + x.w * wf.w;
        #pragma unroll
        for (int off = 32; off; off >>= 1) t += __shfl_xor(t, off, 64);
        if (lane == 0) g[row0 + i] = t;
    }
}

extern "C" void kernel_launch(void* const* d_in, const int* in_sizes, int n_in,
                              void* d_out, int out_size, void* d_ws, size_t ws_size,
                              hipStream_t stream) {
    const float* X = (const float*)d_in[0];   // (16384, 256)
    const float* W = (const float*)d_in[1];   // (256, 256)
    const float* b = (const float*)d_in[2];   // (256,)
    float* out = (float*)d_out;               // (16384,)

    float* slots = (float*)d_ws;              // 64 * 256 floats = 64 KB
    float* w2    = slots + NSLOT * DDIM;      // 256 floats

    hipMemsetAsync(slots, 0, NSLOT * DDIM * sizeof(float), stream);
    k1_v <<<K1BLK, 256, 0, stream>>>(X, b, slots);
    k2_w2<<<NSLOT, 256, 0, stream>>>(slots, W, w2);
    k3_g <<<1024, 256, 0, stream>>>(X, w2, out);
}